// Round 1
// baseline (493.336 us; speedup 1.0000x reference)
//
#include <hip/hip_runtime.h>
#include <hip/hip_bf16.h>

#define N_NODES 50000
#define N_EDGES 800000
#define IN_FEATS 128
#define HD 128            // HEADS*OUT_FEATS
#define NEG_SLOPE 0.2f

// ---------------------------------------------------------------------------
// Transpose the three 128x128 weight matrices: Wt[k][c] = W[c][k]
// out[r][c] = sum_k feat[r][k] * W[c][k] = sum_k feat[r][k] * Wt[k][c]
// ---------------------------------------------------------------------------
__global__ void transpose3_kernel(const float* __restrict__ W0,
                                  const float* __restrict__ W1,
                                  const float* __restrict__ W2,
                                  float* __restrict__ T) {
    int idx = blockIdx.x * 256 + threadIdx.x;          // 0 .. 3*16384-1
    if (idx >= 3 * HD * IN_FEATS) return;
    int m = idx >> 14;                                 // which matrix
    int r = (idx >> 7) & 127;                          // row of W (c of out)
    int c = idx & 127;                                 // col of W (k)
    const float* W = (m == 0) ? W0 : ((m == 1) ? W1 : W2);
    T[(size_t)m * HD * IN_FEATS + (size_t)c * HD + r] = W[(size_t)r * IN_FEATS + c];
}

// ---------------------------------------------------------------------------
// Projection GEMM: out[N,128] = feat[N,128] @ Wt (Wt is [k][c]) + bias
// Block: 256 threads, 64 rows per block. Each thread: 16 rows x 2 cols.
// Within a wave all lanes share the same row set -> LDS reads are broadcasts.
// Wt reads: lanes hold consecutive col pairs -> coalesced float2.
// ---------------------------------------------------------------------------
#define PROJ_ROWS 64
__global__ __launch_bounds__(256) void proj_kernel(
    const float* __restrict__ feat, const float* __restrict__ Wt,
    const float* __restrict__ bias, float* __restrict__ out, int nrows) {
    __shared__ float flds[PROJ_ROWS][IN_FEATS];
    int row0 = blockIdx.x * PROJ_ROWS;
    int tid = threadIdx.x;
    int nrow_blk = nrows - row0; if (nrow_blk > PROJ_ROWS) nrow_blk = PROJ_ROWS;

    // cooperative load of the feat tile (coalesced float4)
    const float4* fsrc = (const float4*)(feat + (size_t)row0 * IN_FEATS);
    float4* fdst4 = (float4*)(&flds[0][0]);
    int n4 = nrow_blk * (IN_FEATS / 4);
    for (int i = tid; i < n4; i += 256) fdst4[i] = fsrc[i];
    __syncthreads();

    int c2 = tid & 63;        // 0..63 -> col pair
    int rg = tid >> 6;        // 0..3  -> row group (uniform per wave)
    int c0 = c2 * 2;

    float acc0[16], acc1[16];
#pragma unroll
    for (int r = 0; r < 16; ++r) { acc0[r] = 0.f; acc1[r] = 0.f; }

    for (int k = 0; k < IN_FEATS; k += 4) {
        float2 w0 = *(const float2*)&Wt[(size_t)(k + 0) * HD + c0];
        float2 w1 = *(const float2*)&Wt[(size_t)(k + 1) * HD + c0];
        float2 w2 = *(const float2*)&Wt[(size_t)(k + 2) * HD + c0];
        float2 w3 = *(const float2*)&Wt[(size_t)(k + 3) * HD + c0];
#pragma unroll
        for (int rr = 0; rr < 16; ++rr) {
            float4 f = *(const float4*)&flds[rg * 16 + rr][k];
            acc0[rr] = fmaf(f.x, w0.x, fmaf(f.y, w1.x, fmaf(f.z, w2.x, fmaf(f.w, w3.x, acc0[rr]))));
            acc1[rr] = fmaf(f.x, w0.y, fmaf(f.y, w1.y, fmaf(f.z, w2.y, fmaf(f.w, w3.y, acc1[rr]))));
        }
    }

    float b0 = bias[c0], b1 = bias[c0 + 1];
#pragma unroll
    for (int rr = 0; rr < 16; ++rr) {
        int r = rg * 16 + rr;
        if (r < nrow_blk) {
            float2 o; o.x = acc0[rr] + b0; o.y = acc1[rr] + b1;
            *(float2*)&out[(size_t)(row0 + r) * HD + c0] = o;
        }
    }
}

// ---------------------------------------------------------------------------
// CSR build: histogram of dst, exclusive scan, scatter src ids sorted by dst
// ---------------------------------------------------------------------------
__global__ void count_kernel(const int* __restrict__ dst, int* __restrict__ cnt, int E) {
    int e = blockIdx.x * blockDim.x + threadIdx.x;
    if (e < E) atomicAdd(&cnt[dst[e]], 1);
}

__global__ __launch_bounds__(1024) void scan_kernel(const int* __restrict__ cnt,
                                                    int* __restrict__ off, int n) {
    __shared__ int sdata[1024];
    __shared__ int s_base;
    int tid = threadIdx.x;
    if (tid == 0) s_base = 0;
    __syncthreads();
    int tiles = (n + 1023) >> 10;
    for (int t = 0; t < tiles; ++t) {
        int i = (t << 10) + tid;
        int v = (i < n) ? cnt[i] : 0;
        sdata[tid] = v;
        __syncthreads();
        for (int ofs = 1; ofs < 1024; ofs <<= 1) {
            int x = (tid >= ofs) ? sdata[tid - ofs] : 0;
            __syncthreads();
            sdata[tid] += x;
            __syncthreads();
        }
        int incl = sdata[tid];
        int base = s_base;
        if (i < n) off[i] = base + incl - v;   // exclusive prefix
        __syncthreads();
        if (tid == 1023) s_base = base + incl;
        __syncthreads();
    }
    if (tid == 0) off[n] = s_base;
}

__global__ void scatter_kernel(const int* __restrict__ src, const int* __restrict__ dst,
                               const int* __restrict__ off, int* __restrict__ cur,
                               int* __restrict__ ssort, int E) {
    int e = blockIdx.x * blockDim.x + threadIdx.x;
    if (e < E) {
        int d = dst[e];
        int p = atomicAdd(&cur[d], 1);
        ssort[off[d] + p] = src[e];
    }
}

// ---------------------------------------------------------------------------
// Gather/aggregate: one wave per dst node, 2 channels per lane (float2).
// Softmax computed without max-subtraction (logits bounded ~|8.6| -> safe fp32)
// num/den accumulated in registers; single write of out = num/den.
// ---------------------------------------------------------------------------
__global__ __launch_bounds__(256) void gather_kernel(
    const float* __restrict__ f_s, const float* __restrict__ f_d,
    const float* __restrict__ f_v, const int* __restrict__ off,
    const int* __restrict__ ssort, float* __restrict__ out, int n) {
    int wid = (int)((blockIdx.x * 256 + threadIdx.x) >> 6);
    int lane = threadIdx.x & 63;
    if (wid >= n) return;
    int c = lane * 2;
    float2 fd = *(const float2*)&f_d[(size_t)wid * HD + c];
    float nx = 0.f, ny = 0.f, dx = 0.f, dy = 0.f;
    int beg = off[wid], end = off[wid + 1];
    for (int i = beg; i < end; ++i) {
        int s = ssort[i];
        float2 fs = *(const float2*)&f_s[(size_t)s * HD + c];
        float2 fv = *(const float2*)&f_v[(size_t)s * HD + c];
        float a0 = fs.x + fd.x, a1 = fs.y + fd.y;
        a0 = (a0 >= 0.f) ? a0 : NEG_SLOPE * a0;
        a1 = (a1 >= 0.f) ? a1 : NEG_SLOPE * a1;
        float x0 = __expf(a0), x1 = __expf(a1);
        dx += x0; dy += x1;
        nx = fmaf(x0, fv.x, nx); ny = fmaf(x1, fv.y, ny);
    }
    float2 o;
    o.x = (dx > 0.f) ? nx / dx : 0.f;
    o.y = (dy > 0.f) ? ny / dy : 0.f;
    *(float2*)&out[(size_t)wid * HD + c] = o;
}

// ---------------------------------------------------------------------------
extern "C" void kernel_launch(void* const* d_in, const int* in_sizes, int n_in,
                              void* d_out, int out_size, void* d_ws, size_t ws_size,
                              hipStream_t stream) {
    const float* feat  = (const float*)d_in[0];
    const float* W_src = (const float*)d_in[1];
    const float* b_src = (const float*)d_in[2];
    const float* W_dst = (const float*)d_in[3];
    const float* b_dst = (const float*)d_in[4];
    const float* W_v   = (const float*)d_in[5];
    const float* b_v   = (const float*)d_in[6];
    const int*   src   = (const int*)d_in[7];
    const int*   dst   = (const int*)d_in[8];
    float* out = (float*)d_out;

    // workspace layout
    float* f_s = (float*)d_ws;                       // 6.4M floats
    float* f_d = f_s + (size_t)N_NODES * HD;         // 6.4M
    float* f_v = f_d + (size_t)N_NODES * HD;         // 6.4M
    float* wt  = f_v + (size_t)N_NODES * HD;         // 3*16384
    int*   cnt = (int*)(wt + 3 * HD * IN_FEATS);     // 50000
    int*   cur = cnt + N_NODES;                      // 50000
    int*   off = cur + N_NODES;                      // 50001
    int*   ssort = off + (N_NODES + 1);              // 800000

    // zero histogram + cursor (adjacent)
    hipMemsetAsync(cnt, 0, 2 * (size_t)N_NODES * sizeof(int), stream);

    // transpose weights
    transpose3_kernel<<<(3 * HD * IN_FEATS + 255) / 256, 256, 0, stream>>>(
        W_src, W_dst, W_v, wt);

    // projections
    int pgrid = (N_NODES + PROJ_ROWS - 1) / PROJ_ROWS;
    proj_kernel<<<pgrid, 256, 0, stream>>>(feat, wt,                    b_src, f_s, N_NODES);
    proj_kernel<<<pgrid, 256, 0, stream>>>(feat, wt + HD * IN_FEATS,    b_dst, f_d, N_NODES);
    proj_kernel<<<pgrid, 256, 0, stream>>>(feat, wt + 2 * HD * IN_FEATS, b_v,  f_v, N_NODES);

    // CSR by dst
    int egrid = (N_EDGES + 255) / 256;
    count_kernel<<<egrid, 256, 0, stream>>>(dst, cnt, N_EDGES);
    scan_kernel<<<1, 1024, 0, stream>>>(cnt, off, N_NODES);
    scatter_kernel<<<egrid, 256, 0, stream>>>(src, dst, off, cur, ssort, N_EDGES);

    // aggregate
    int ggrid = (N_NODES * 64 + 255) / 256;
    gather_kernel<<<ggrid, 256, 0, stream>>>(f_s, f_d, f_v, off, ssort, out, N_NODES);
}

// Round 2
// 350.654 us; speedup vs baseline: 1.4069x; 1.4069x over previous
//
#include <hip/hip_runtime.h>
#include <hip/hip_bf16.h>

#define N_NODES 50000
#define N_EDGES 800000
#define IN_FEATS 128
#define HD 128            // HEADS*OUT_FEATS
#define NEG_SLOPE 0.2f

// gsv layout: per node 768 bytes = [128 x f32 f_src][128 x bf16 f_v]
#define GSV_STRIDE 768

static __device__ __forceinline__ unsigned short f2bf(float x) {
    unsigned int u = __float_as_uint(x);
    unsigned int r = (u + 0x7FFFu + ((u >> 16) & 1u)) >> 16;   // RN-even
    return (unsigned short)r;
}

// ---------------------------------------------------------------------------
// Transpose the three 128x128 weight matrices: Wt[k][c] = W[c][k]
// ---------------------------------------------------------------------------
__global__ void transpose3_kernel(const float* __restrict__ W0,
                                  const float* __restrict__ W1,
                                  const float* __restrict__ W2,
                                  float* __restrict__ T) {
    int idx = blockIdx.x * 256 + threadIdx.x;
    if (idx >= 3 * HD * IN_FEATS) return;
    int m = idx >> 14;
    int r = (idx >> 7) & 127;
    int c = idx & 127;
    const float* W = (m == 0) ? W0 : ((m == 1) ? W1 : W2);
    T[(size_t)m * HD * IN_FEATS + (size_t)c * HD + r] = W[(size_t)r * IN_FEATS + c];
}

// ---------------------------------------------------------------------------
// Fused projection: out = feat @ {W_src,W_dst,W_v}^T + b, sharing the LDS
// feat tile across all three GEMMs.
//   m=0 (src) -> gsv fp32 half;  m=1 (dst) -> f_d fp32 rows;  m=2 (v) -> gsv bf16 half
// Block: 256 threads, 64 rows. Thread: 16 rows x 2 cols x 3 matrices.
// ---------------------------------------------------------------------------
#define PROJ_ROWS 64
__global__ __launch_bounds__(256) void proj3_kernel(
    const float* __restrict__ feat, const float* __restrict__ Wt,
    const float* __restrict__ b_src, const float* __restrict__ b_dst,
    const float* __restrict__ b_v,
    char* __restrict__ gsv, float* __restrict__ f_d, int nrows) {
    __shared__ float flds[PROJ_ROWS][IN_FEATS];
    int row0 = blockIdx.x * PROJ_ROWS;
    int tid = threadIdx.x;
    int nrow_blk = nrows - row0; if (nrow_blk > PROJ_ROWS) nrow_blk = PROJ_ROWS;

    const float4* fsrc = (const float4*)(feat + (size_t)row0 * IN_FEATS);
    float4* fdst4 = (float4*)(&flds[0][0]);
    int n4 = nrow_blk * (IN_FEATS / 4);
    for (int i = tid; i < n4; i += 256) fdst4[i] = fsrc[i];
    __syncthreads();

    int c2 = tid & 63;        // col pair index (= lane)
    int rg = tid >> 6;        // row group, uniform per wave
    int c0 = c2 * 2;

    float acc0[3][16], acc1[3][16];
#pragma unroll
    for (int m = 0; m < 3; ++m)
#pragma unroll
        for (int r = 0; r < 16; ++r) { acc0[m][r] = 0.f; acc1[m][r] = 0.f; }

#pragma unroll 1
    for (int k = 0; k < IN_FEATS; k += 4) {
        float2 w[3][4];
#pragma unroll
        for (int m = 0; m < 3; ++m) {
            const float* wb = Wt + (size_t)m * HD * IN_FEATS;
#pragma unroll
            for (int kk = 0; kk < 4; ++kk)
                w[m][kk] = *(const float2*)&wb[(size_t)(k + kk) * HD + c0];
        }
#pragma unroll
        for (int rr = 0; rr < 16; ++rr) {
            float4 f = *(const float4*)&flds[rg * 16 + rr][k];
#pragma unroll
            for (int m = 0; m < 3; ++m) {
                acc0[m][rr] = fmaf(f.x, w[m][0].x, fmaf(f.y, w[m][1].x,
                              fmaf(f.z, w[m][2].x, fmaf(f.w, w[m][3].x, acc0[m][rr]))));
                acc1[m][rr] = fmaf(f.x, w[m][0].y, fmaf(f.y, w[m][1].y,
                              fmaf(f.z, w[m][2].y, fmaf(f.w, w[m][3].y, acc1[m][rr]))));
            }
        }
    }

    float bs0 = b_src[c0], bs1 = b_src[c0 + 1];
    float bd0 = b_dst[c0], bd1 = b_dst[c0 + 1];
    float bv0 = b_v[c0],   bv1 = b_v[c0 + 1];
#pragma unroll
    for (int rr = 0; rr < 16; ++rr) {
        int r = rg * 16 + rr;
        if (r < nrow_blk) {
            size_t row = (size_t)(row0 + r);
            // f_src -> gsv fp32 half
            float2 os; os.x = acc0[0][rr] + bs0; os.y = acc1[0][rr] + bs1;
            *(float2*)(gsv + row * GSV_STRIDE + c2 * 8) = os;
            // f_dst -> plain fp32 rows
            float2 od; od.x = acc0[1][rr] + bd0; od.y = acc1[1][rr] + bd1;
            *(float2*)&f_d[row * HD + c0] = od;
            // f_v -> gsv bf16 half
            unsigned int pv = (unsigned int)f2bf(acc0[2][rr] + bv0) |
                              ((unsigned int)f2bf(acc1[2][rr] + bv1) << 16);
            *(unsigned int*)(gsv + row * GSV_STRIDE + 512 + c2 * 4) = pv;
        }
    }
}

// ---------------------------------------------------------------------------
// CSR build: histogram, 3-phase multi-block exclusive scan, scatter
// ---------------------------------------------------------------------------
__global__ void count_kernel(const int* __restrict__ dst, int* __restrict__ cnt, int E) {
    int e = blockIdx.x * blockDim.x + threadIdx.x;
    if (e < E) atomicAdd(&cnt[dst[e]], 1);
}

// phase 1: per-block (256 counts) sums
__global__ __launch_bounds__(256) void scan_partial(const int* __restrict__ cnt,
                                                    int* __restrict__ bsum, int n) {
    int i = blockIdx.x * 256 + threadIdx.x;
    int v = (i < n) ? cnt[i] : 0;
#pragma unroll
    for (int d = 32; d > 0; d >>= 1) v += __shfl_down(v, d);
    __shared__ int ws[4];
    int lane = threadIdx.x & 63, w = threadIdx.x >> 6;
    if (lane == 0) ws[w] = v;
    __syncthreads();
    if (threadIdx.x == 0) bsum[blockIdx.x] = ws[0] + ws[1] + ws[2] + ws[3];
}

// phase 2: exclusive scan of block sums (nb <= 256), also writes off[n]=total
__global__ __launch_bounds__(256) void scan_base(int* __restrict__ bsum, int nb,
                                                 int* __restrict__ off, int n) {
    __shared__ int s[256];
    int t = threadIdx.x;
    int v = (t < nb) ? bsum[t] : 0;
    s[t] = v;
    __syncthreads();
#pragma unroll
    for (int d = 1; d < 256; d <<= 1) {
        int x = (t >= d) ? s[t - d] : 0;
        __syncthreads();
        s[t] += x;
        __syncthreads();
    }
    if (t < nb) bsum[t] = s[t] - v;          // exclusive
    if (t == 255) off[n] = s[255];           // grand total
}

// phase 3: per-block exclusive scan + base, write offsets
__global__ __launch_bounds__(256) void scan_write(const int* __restrict__ cnt,
                                                  const int* __restrict__ bsum,
                                                  int* __restrict__ off, int n) {
    int i = blockIdx.x * 256 + threadIdx.x;
    int v = (i < n) ? cnt[i] : 0;
    int lane = threadIdx.x & 63, w = threadIdx.x >> 6;
    int x = v;
#pragma unroll
    for (int d = 1; d < 64; d <<= 1) {
        int up = __shfl_up(x, d);
        if (lane >= d) x += up;
    }
    __shared__ int ws[4];
    if (lane == 63) ws[w] = x;
    __syncthreads();
    int base = bsum[blockIdx.x];
    for (int ww = 0; ww < w; ++ww) base += ws[ww];
    if (i < n) off[i] = base + x - v;
}

__global__ void scatter_kernel(const int* __restrict__ src, const int* __restrict__ dst,
                               const int* __restrict__ off, int* __restrict__ cur,
                               int* __restrict__ ssort, int E) {
    int e = blockIdx.x * blockDim.x + threadIdx.x;
    if (e < E) {
        int d = dst[e];
        int p = atomicAdd(&cur[d], 1);
        ssort[off[d] + p] = src[e];
    }
}

// ---------------------------------------------------------------------------
// Gather/aggregate: one wave per dst node, 2 channels per lane.
// Reads one contiguous 768B row per edge (fs fp32 + fv bf16), softmax w/o max.
// ---------------------------------------------------------------------------
__global__ __launch_bounds__(256) void gather_kernel(
    const char* __restrict__ gsv, const float* __restrict__ f_d,
    const int* __restrict__ off, const int* __restrict__ ssort,
    float* __restrict__ out, int n) {
    int wid = (int)((blockIdx.x * 256 + threadIdx.x) >> 6);
    int lane = threadIdx.x & 63;
    if (wid >= n) return;
    int c = lane * 2;
    float2 fd = *(const float2*)&f_d[(size_t)wid * HD + c];
    float nx = 0.f, ny = 0.f, dx = 0.f, dy = 0.f;
    int beg = off[wid], end = off[wid + 1];
    int i = beg;
    int s_next = (i < end) ? ssort[i] : 0;
    while (i < end) {
        int s = s_next;
        ++i;
        if (i < end) s_next = ssort[i];
        const char* base = gsv + (size_t)s * GSV_STRIDE;
        float2 fs = *(const float2*)(base + lane * 8);
        unsigned int pv = *(const unsigned int*)(base + 512 + lane * 4);
        float v0 = __uint_as_float(pv << 16);
        float v1 = __uint_as_float(pv & 0xFFFF0000u);
        float a0 = fs.x + fd.x, a1 = fs.y + fd.y;
        a0 = (a0 >= 0.f) ? a0 : NEG_SLOPE * a0;
        a1 = (a1 >= 0.f) ? a1 : NEG_SLOPE * a1;
        float x0 = __expf(a0), x1 = __expf(a1);
        dx += x0; dy += x1;
        nx = fmaf(x0, v0, nx); ny = fmaf(x1, v1, ny);
    }
    float2 o;
    o.x = (dx > 0.f) ? nx / dx : 0.f;
    o.y = (dy > 0.f) ? ny / dy : 0.f;
    *(float2*)&out[(size_t)wid * HD + c] = o;
}

// ---------------------------------------------------------------------------
extern "C" void kernel_launch(void* const* d_in, const int* in_sizes, int n_in,
                              void* d_out, int out_size, void* d_ws, size_t ws_size,
                              hipStream_t stream) {
    const float* feat  = (const float*)d_in[0];
    const float* W_src = (const float*)d_in[1];
    const float* b_src = (const float*)d_in[2];
    const float* W_dst = (const float*)d_in[3];
    const float* b_dst = (const float*)d_in[4];
    const float* W_v   = (const float*)d_in[5];
    const float* b_v   = (const float*)d_in[6];
    const int*   src   = (const int*)d_in[7];
    const int*   dst   = (const int*)d_in[8];
    float* out = (float*)d_out;

    // workspace layout
    float* f_d = (float*)d_ws;                          // N*128 f32 = 25.6 MB
    char*  gsv = (char*)(f_d + (size_t)N_NODES * HD);   // N*768 B   = 38.4 MB
    float* wt  = (float*)(gsv + (size_t)N_NODES * GSV_STRIDE); // 3*16384 f32
    int*   cnt = (int*)(wt + 3 * HD * IN_FEATS);        // N
    int*   cur = cnt + N_NODES;                         // N
    int*   off = cur + N_NODES;                         // N+1
    int*   bsum = off + (N_NODES + 1);                  // 256
    int*   ssort = bsum + 256;                          // E

    const int nb = (N_NODES + 255) / 256;               // 196 scan blocks

    hipMemsetAsync(cnt, 0, 2 * (size_t)N_NODES * sizeof(int), stream);

    transpose3_kernel<<<(3 * HD * IN_FEATS + 255) / 256, 256, 0, stream>>>(
        W_src, W_dst, W_v, wt);

    int pgrid = (N_NODES + PROJ_ROWS - 1) / PROJ_ROWS;
    proj3_kernel<<<pgrid, 256, 0, stream>>>(feat, wt, b_src, b_dst, b_v, gsv, f_d, N_NODES);

    int egrid = (N_EDGES + 255) / 256;
    count_kernel<<<egrid, 256, 0, stream>>>(dst, cnt, N_EDGES);
    scan_partial<<<nb, 256, 0, stream>>>(cnt, bsum, N_NODES);
    scan_base<<<1, 256, 0, stream>>>(bsum, nb, off, N_NODES);
    scan_write<<<nb, 256, 0, stream>>>(cnt, bsum, off, N_NODES);
    scatter_kernel<<<egrid, 256, 0, stream>>>(src, dst, off, cur, ssort, N_EDGES);

    int ggrid = (N_NODES * 64 + 255) / 256;
    gather_kernel<<<ggrid, 256, 0, stream>>>(gsv, f_d, off, ssort, out, N_NODES);
}

// Round 3
// 267.955 us; speedup vs baseline: 1.8411x; 1.3086x over previous
//
#include <hip/hip_runtime.h>
#include <hip/hip_bf16.h>
#include <hip/hip_fp16.h>

#define N_NODES 50000
#define N_EDGES 800000
#define IN_FEATS 128
#define HD 128            // HEADS*OUT_FEATS
#define NTOT 384          // 3 * HD (src, dst, v concatenated)
#define NEG_SLOPE 0.2f

typedef __attribute__((ext_vector_type(8))) short bf16x8;
typedef __attribute__((ext_vector_type(4))) float floatx4;

static __device__ __forceinline__ unsigned short f2bf(float x) {
    unsigned int u = __float_as_uint(x);
    unsigned int r = (u + 0x7FFFu + ((u >> 16) & 1u)) >> 16;   // RN-even
    return (unsigned short)r;
}
static __device__ __forceinline__ float bf2f(unsigned short h) {
    return __uint_as_float((unsigned int)h << 16);
}

// ---------------------------------------------------------------------------
// Pre-swizzle B = [Wt_src | Wt_dst | Wt_v] (bf16) into MFMA B-fragment order:
// Bsw[((t*4+q)*64 + lane)*8 + j] = B[k][n],  k = q*32 + (lane>>4)*8 + j,
// n = t*16 + (lane&15);  B[k][n] = W_m[c][k], m = n>>7, c = n&127.
// One dwordx4 per lane then feeds each mfma B operand directly.
// ---------------------------------------------------------------------------
__global__ __launch_bounds__(256) void prep_kernel(
    const float* __restrict__ W0, const float* __restrict__ W1,
    const float* __restrict__ W2, unsigned short* __restrict__ Bsw) {
    int idx = blockIdx.x * 256 + threadIdx.x;      // 0 .. 49151
    int j = idx & 7;
    int l = (idx >> 3) & 63;
    int q = (idx >> 9) & 3;
    int t = idx >> 11;                              // 0..23
    int k = q * 32 + ((l >> 4) << 3) + j;
    int n = t * 16 + (l & 15);
    int m = n >> 7;
    int c = n & 127;
    const float* W = (m == 0) ? W0 : ((m == 1) ? W1 : W2);
    Bsw[idx] = f2bf(W[(size_t)c * IN_FEATS + k]);
}

// ---------------------------------------------------------------------------
// MFMA projection: C[50000, 384] = feat[50000,128] @ B[128,384] + bias.
// One wave per 16-row tile; 24 N-tiles sequentially. A split into bf16 hi+lo
// (2 MFMAs per K-chunk) for ~fp32 logit accuracy. Outputs stored fp16:
//   n-tile 0..7  -> f_src  half of gsv (interleaved)
//   n-tile 8..15 -> f_dst  array fdh
//   n-tile 16..23-> f_v    half of gsv (interleaved)
// gsv layout per node: 64 groups of 4 halves {fs[2c],fs[2c+1],fv[2c],fv[2c+1]}
// ---------------------------------------------------------------------------
__global__ __launch_bounds__(256) void proj_mfma_kernel(
    const float* __restrict__ feat, const unsigned short* __restrict__ Bsw,
    const float* __restrict__ b_src, const float* __restrict__ b_dst,
    const float* __restrict__ b_v,
    unsigned short* __restrict__ gsv, unsigned short* __restrict__ fdh) {
    int wave = threadIdx.x >> 6;
    int lane = threadIdx.x & 63;
    int tile = blockIdx.x * 4 + wave;
    int row0 = tile * 16;
    if (row0 >= N_NODES) return;
    int r16 = lane & 15;
    int quad = lane >> 4;

    // Build A fragments: lane holds A[row0 + r16][k = q*32 + quad*8 + j]
    bf16x8 Ah[4], Al[4];
    const float* arow = feat + (size_t)(row0 + r16) * IN_FEATS + quad * 8;
#pragma unroll
    for (int q = 0; q < 4; ++q) {
        float4 x0 = *(const float4*)(arow + q * 32);
        float4 x1 = *(const float4*)(arow + q * 32 + 4);
        float xs[8] = {x0.x, x0.y, x0.z, x0.w, x1.x, x1.y, x1.z, x1.w};
#pragma unroll
        for (int j = 0; j < 8; ++j) {
            unsigned short h = f2bf(xs[j]);
            Ah[q][j] = (short)h;
            Al[q][j] = (short)f2bf(xs[j] - bf2f(h));
        }
    }

#pragma unroll 1
    for (int t = 0; t < 24; ++t) {
        floatx4 acc = {0.f, 0.f, 0.f, 0.f};
#pragma unroll
        for (int q = 0; q < 4; ++q) {
            bf16x8 bf = *(const bf16x8*)(Bsw + (((size_t)(t * 4 + q) * 64 + lane) << 3));
            acc = __builtin_amdgcn_mfma_f32_16x16x32_bf16(Ah[q], bf, acc, 0, 0, 0);
            acc = __builtin_amdgcn_mfma_f32_16x16x32_bf16(Al[q], bf, acc, 0, 0, 0);
        }
        // epilogue: D[row = quad*4 + r][col = r16]; m uniform per tile
        int m = t >> 3;
        int c = ((t & 7) << 4) + r16;
        const float* bias = (m == 0) ? b_src : ((m == 1) ? b_dst : b_v);
        float bv = bias[c];
#pragma unroll
        for (int r = 0; r < 4; ++r) {
            size_t row = (size_t)(row0 + quad * 4 + r);
            float val = acc[r] + bv;
            unsigned short h = __half_as_ushort(__float2half(val));
            if (m == 0)      gsv[row * 256 + ((c >> 1) << 2) + (c & 1)] = h;
            else if (m == 1) fdh[row * 128 + c] = h;
            else             gsv[row * 256 + ((c >> 1) << 2) + 2 + (c & 1)] = h;
        }
    }
}

// ---------------------------------------------------------------------------
// CSR build: histogram, 3-phase multi-block exclusive scan, scatter
// ---------------------------------------------------------------------------
__global__ void count_kernel(const int* __restrict__ dst, int* __restrict__ cnt, int E) {
    int e = blockIdx.x * blockDim.x + threadIdx.x;
    if (e < E) atomicAdd(&cnt[dst[e]], 1);
}

__global__ __launch_bounds__(256) void scan_partial(const int* __restrict__ cnt,
                                                    int* __restrict__ bsum, int n) {
    int i = blockIdx.x * 256 + threadIdx.x;
    int v = (i < n) ? cnt[i] : 0;
#pragma unroll
    for (int d = 32; d > 0; d >>= 1) v += __shfl_down(v, d);
    __shared__ int ws[4];
    int lane = threadIdx.x & 63, w = threadIdx.x >> 6;
    if (lane == 0) ws[w] = v;
    __syncthreads();
    if (threadIdx.x == 0) bsum[blockIdx.x] = ws[0] + ws[1] + ws[2] + ws[3];
}

__global__ __launch_bounds__(256) void scan_base(int* __restrict__ bsum, int nb,
                                                 int* __restrict__ off, int n) {
    __shared__ int s[256];
    int t = threadIdx.x;
    int v = (t < nb) ? bsum[t] : 0;
    s[t] = v;
    __syncthreads();
#pragma unroll
    for (int d = 1; d < 256; d <<= 1) {
        int x = (t >= d) ? s[t - d] : 0;
        __syncthreads();
        s[t] += x;
        __syncthreads();
    }
    if (t < nb) bsum[t] = s[t] - v;          // exclusive
    if (t == 255) off[n] = s[255];           // grand total
}

__global__ __launch_bounds__(256) void scan_write(const int* __restrict__ cnt,
                                                  const int* __restrict__ bsum,
                                                  int* __restrict__ off, int n) {
    int i = blockIdx.x * 256 + threadIdx.x;
    int v = (i < n) ? cnt[i] : 0;
    int lane = threadIdx.x & 63, w = threadIdx.x >> 6;
    int x = v;
#pragma unroll
    for (int d = 1; d < 64; d <<= 1) {
        int up = __shfl_up(x, d);
        if (lane >= d) x += up;
    }
    __shared__ int ws[4];
    if (lane == 63) ws[w] = x;
    __syncthreads();
    int base = bsum[blockIdx.x];
    for (int ww = 0; ww < w; ++ww) base += ws[ww];
    if (i < n) off[i] = base + x - v;
}

__global__ void scatter_kernel(const int* __restrict__ src, const int* __restrict__ dst,
                               const int* __restrict__ off, int* __restrict__ cur,
                               int* __restrict__ ssort, int E) {
    int e = blockIdx.x * blockDim.x + threadIdx.x;
    if (e < E) {
        int d = dst[e];
        int p = atomicAdd(&cur[d], 1);
        ssort[off[d] + p] = src[e];
    }
}

// ---------------------------------------------------------------------------
// Gather/aggregate: one wave per dst node, channel pair per lane.
// One dwordx2 per edge per lane: {fs0,fs1,fv0,fv1} fp16. Softmax w/o max.
// ---------------------------------------------------------------------------
__global__ __launch_bounds__(256) void gather_kernel(
    const unsigned short* __restrict__ gsv, const unsigned short* __restrict__ fdh,
    const int* __restrict__ off, const int* __restrict__ ssort,
    float* __restrict__ out, int n) {
    int wid = (int)((blockIdx.x * 256 + threadIdx.x) >> 6);
    int lane = threadIdx.x & 63;
    if (wid >= n) return;
    float2 fd = __half22float2(*(const __half2*)(fdh + (size_t)wid * 128 + lane * 2));
    float nx = 0.f, ny = 0.f, dx = 0.f, dy = 0.f;
    int beg = off[wid], end = off[wid + 1];
    int i = beg;
    int s_next = (i < end) ? ssort[i] : 0;
    while (i < end) {
        int s = s_next;
        ++i;
        if (i < end) s_next = ssort[i];
        uint2 g = *(const uint2*)(gsv + (size_t)s * 256 + lane * 4);
        float2 fs = __half22float2(*(const __half2*)&g.x);
        float2 fv = __half22float2(*(const __half2*)&g.y);
        float a0 = fs.x + fd.x, a1 = fs.y + fd.y;
        a0 = (a0 >= 0.f) ? a0 : NEG_SLOPE * a0;
        a1 = (a1 >= 0.f) ? a1 : NEG_SLOPE * a1;
        float x0 = __expf(a0), x1 = __expf(a1);
        dx += x0; dy += x1;
        nx = fmaf(x0, fv.x, nx); ny = fmaf(x1, fv.y, ny);
    }
    float2 o;
    o.x = (dx > 0.f) ? nx / dx : 0.f;
    o.y = (dy > 0.f) ? ny / dy : 0.f;
    *(float2*)&out[(size_t)wid * HD + lane * 2] = o;
}

// ---------------------------------------------------------------------------
extern "C" void kernel_launch(void* const* d_in, const int* in_sizes, int n_in,
                              void* d_out, int out_size, void* d_ws, size_t ws_size,
                              hipStream_t stream) {
    const float* feat  = (const float*)d_in[0];
    const float* W_src = (const float*)d_in[1];
    const float* b_src = (const float*)d_in[2];
    const float* W_dst = (const float*)d_in[3];
    const float* b_dst = (const float*)d_in[4];
    const float* W_v   = (const float*)d_in[5];
    const float* b_v   = (const float*)d_in[6];
    const int*   src   = (const int*)d_in[7];
    const int*   dst   = (const int*)d_in[8];
    float* out = (float*)d_out;

    // workspace layout
    unsigned short* gsv = (unsigned short*)d_ws;                 // N*256 u16 = 25.6 MB
    unsigned short* fdh = gsv + (size_t)N_NODES * 256;           // N*128 u16 = 12.8 MB
    unsigned short* Bsw = fdh + (size_t)N_NODES * 128;           // 49152 u16 = 96 KB
    int*   cnt  = (int*)(Bsw + 24 * 4 * 64 * 8);                 // N
    int*   cur  = cnt + N_NODES;                                 // N
    int*   off  = cur + N_NODES;                                 // N+1
    int*   bsum = off + (N_NODES + 1);                           // 256
    int*   ssort = bsum + 256;                                   // E

    const int nb = (N_NODES + 255) / 256;                        // 196

    hipMemsetAsync(cnt, 0, 2 * (size_t)N_NODES * sizeof(int), stream);

    prep_kernel<<<192, 256, 0, stream>>>(W_src, W_dst, W_v, Bsw);

    int pgrid = (N_NODES / 16 + 3) / 4;                          // 782
    proj_mfma_kernel<<<pgrid, 256, 0, stream>>>(feat, Bsw, b_src, b_dst, b_v, gsv, fdh);

    int egrid = (N_EDGES + 255) / 256;
    count_kernel<<<egrid, 256, 0, stream>>>(dst, cnt, N_EDGES);
    scan_partial<<<nb, 256, 0, stream>>>(cnt, bsum, N_NODES);
    scan_base<<<1, 256, 0, stream>>>(bsum, nb, off, N_NODES);
    scan_write<<<nb, 256, 0, stream>>>(cnt, bsum, off, N_NODES);
    scatter_kernel<<<egrid, 256, 0, stream>>>(src, dst, off, cur, ssort, N_EDGES);

    int ggrid = (N_NODES * 64 + 255) / 256;
    gather_kernel<<<ggrid, 256, 0, stream>>>(gsv, fdh, off, ssort, out, N_NODES);
}

// Round 4
// 248.635 us; speedup vs baseline: 1.9842x; 1.0777x over previous
//
#include <hip/hip_runtime.h>
#include <hip/hip_fp16.h>

#define N_NODES 50000
#define N_EDGES 800000
#define IN_FEATS 128
#define HD 128            // HEADS*OUT_FEATS
#define LOG2E 1.4426950408889634f

typedef __attribute__((ext_vector_type(8))) short bf16x8;
typedef __attribute__((ext_vector_type(4))) float floatx4;

#if __has_builtin(__builtin_amdgcn_exp2f)
#define EXP2F(x) __builtin_amdgcn_exp2f(x)
#else
#define EXP2F(x) __expf((x) * 0.6931471805599453f)
#endif

static __device__ __forceinline__ unsigned short f2bf(float x) {
    unsigned int u = __float_as_uint(x);
    return (unsigned short)((u + 0x7FFFu + ((u >> 16) & 1u)) >> 16);   // RN-even
}
static __device__ __forceinline__ float bf2f(unsigned short h) {
    return __uint_as_float((unsigned int)h << 16);
}
static __device__ __forceinline__ unsigned int pk(float a, float b) {
    return (unsigned int)__half_as_ushort(__float2half(a)) |
           ((unsigned int)__half_as_ushort(__float2half(b)) << 16);
}

// ---------------------------------------------------------------------------
// prep: swizzle W into MFMA A-operand fragment order (bf16), pre-scaled by
// log2e for src/dst (softmax exp -> exp2); also zero cnt/cur (folds memset).
// A[m][k]: m = ch-in-tile = lane&15, k = q*32 + (lane>>4)*8 + j.
// Bsw[((t*4+q)*64 + l)*8 + j] = W_m[(t&7)*16 + (l&15)][q*32 + ((l>>4)<<3) + j]
// ---------------------------------------------------------------------------
__global__ __launch_bounds__(256) void prep_zero_kernel(
    const float* __restrict__ W0, const float* __restrict__ W1,
    const float* __restrict__ W2, unsigned short* __restrict__ Bsw,
    int* __restrict__ cnt, int* __restrict__ cur) {
    int idx = blockIdx.x * 256 + threadIdx.x;
    if (idx < N_NODES) { cnt[idx] = 0; cur[idx] = 0; }
    if (idx < 24 * 4 * 64 * 8) {
        int j = idx & 7;
        int l = (idx >> 3) & 63;
        int q = (idx >> 9) & 3;
        int t = idx >> 11;                       // 0..23
        int k = q * 32 + ((l >> 4) << 3) + j;
        int c = ((t & 7) << 4) + (l & 15);
        int m = t >> 3;
        const float* W = (m == 0) ? W0 : ((m == 1) ? W1 : W2);
        float w = W[(size_t)c * IN_FEATS + k];
        if (m < 2) w *= LOG2E;                   // pre-scale logits for exp2
        Bsw[idx] = f2bf(w);
    }
}

// ---------------------------------------------------------------------------
// Fused projection + edge count.
// Proj (blocks < PGRID): D = W . feat^T via mfma_16x16x32_bf16, A=weights,
// B=feat (hi/lo bf16 split for ~fp32 accuracy). D[ch=quad*4+j][node=lane&15]
// -> each lane holds 4 consecutive channels of one node: dwordx4 store to
// interleaved gsv {fs0,fs1,fv0,fv1,...} and dwordx2 to fdh. No LDS.
// Count (blocks >= PGRID): histogram of dst.
// ---------------------------------------------------------------------------
#define PGRID 782        // ceil((N_NODES/16)/4)
#define CGRID 391        // 391*256*8 >= N_EDGES
__global__ __launch_bounds__(256) void projcount_kernel(
    const float* __restrict__ feat, const unsigned short* __restrict__ Bsw,
    const float* __restrict__ b_src, const float* __restrict__ b_dst,
    const float* __restrict__ b_v,
    unsigned short* __restrict__ gsv, unsigned short* __restrict__ fdh,
    const int* __restrict__ dst, int* __restrict__ cnt) {
    if (blockIdx.x >= PGRID) {
        int base = (blockIdx.x - PGRID) * 2048 + threadIdx.x;
#pragma unroll
        for (int ii = 0; ii < 8; ++ii) {
            int e = base + ii * 256;
            if (e < N_EDGES) atomicAdd(&cnt[dst[e]], 1);
        }
        return;
    }
    int wave = threadIdx.x >> 6, lane = threadIdx.x & 63;
    int tile = blockIdx.x * 4 + wave;
    if (tile >= N_NODES / 16) return;
    int row0 = tile * 16;
    int r16 = lane & 15, quad = lane >> 4;
    size_t node = (size_t)(row0 + r16);

    // feat fragments (B-operand): B[k = quad*8+j][n = r16], hi/lo split
    bf16x8 Fh[4], Fl[4];
    const float* frow = feat + node * IN_FEATS + quad * 8;
#pragma unroll
    for (int q = 0; q < 4; ++q) {
        float4 x0 = *(const float4*)(frow + q * 32);
        float4 x1 = *(const float4*)(frow + q * 32 + 4);
        float xs[8] = {x0.x, x0.y, x0.z, x0.w, x1.x, x1.y, x1.z, x1.w};
#pragma unroll
        for (int j = 0; j < 8; ++j) {
            unsigned short h = f2bf(xs[j]);
            Fh[q][j] = (short)h;
            Fl[q][j] = (short)f2bf(xs[j] - bf2f(h));
        }
    }

#pragma unroll 1
    for (int tt = 0; tt < 8; ++tt) {
        floatx4 as = {0.f,0.f,0.f,0.f}, ad = {0.f,0.f,0.f,0.f}, av = {0.f,0.f,0.f,0.f};
#pragma unroll
        for (int q = 0; q < 4; ++q) {
            bf16x8 ws = *(const bf16x8*)(Bsw + ((((tt)      * 4 + q) * 64 + lane) << 3));
            bf16x8 wd = *(const bf16x8*)(Bsw + ((((8 + tt)  * 4 + q) * 64 + lane) << 3));
            bf16x8 wv = *(const bf16x8*)(Bsw + ((((16 + tt) * 4 + q) * 64 + lane) << 3));
            as = __builtin_amdgcn_mfma_f32_16x16x32_bf16(ws, Fh[q], as, 0, 0, 0);
            as = __builtin_amdgcn_mfma_f32_16x16x32_bf16(ws, Fl[q], as, 0, 0, 0);
            ad = __builtin_amdgcn_mfma_f32_16x16x32_bf16(wd, Fh[q], ad, 0, 0, 0);
            ad = __builtin_amdgcn_mfma_f32_16x16x32_bf16(wd, Fl[q], ad, 0, 0, 0);
            av = __builtin_amdgcn_mfma_f32_16x16x32_bf16(wv, Fh[q], av, 0, 0, 0);
            av = __builtin_amdgcn_mfma_f32_16x16x32_bf16(wv, Fl[q], av, 0, 0, 0);
        }
        int cbase = (tt << 4) + (quad << 2);        // 4 consecutive channels
        float4 bs = *(const float4*)(b_src + cbase);
        float4 bd = *(const float4*)(b_dst + cbase);
        float4 bv = *(const float4*)(b_v   + cbase);
        uint4 o;
        o.x = pk(as[0] + bs.x * LOG2E, as[1] + bs.y * LOG2E);
        o.y = pk(av[0] + bv.x,         av[1] + bv.y);
        o.z = pk(as[2] + bs.z * LOG2E, as[3] + bs.w * LOG2E);
        o.w = pk(av[2] + bv.z,         av[3] + bv.w);
        *(uint4*)(gsv + node * 256 + (cbase << 1)) = o;     // 16B aligned
        uint2 od;
        od.x = pk(ad[0] + bd.x * LOG2E, ad[1] + bd.y * LOG2E);
        od.y = pk(ad[2] + bd.z * LOG2E, ad[3] + bd.w * LOG2E);
        *(uint2*)(fdh + node * 128 + cbase) = od;           // 8B aligned
    }
}

// ---------------------------------------------------------------------------
// scan phase 1: per-block sums of cnt (256 each)
// ---------------------------------------------------------------------------
__global__ __launch_bounds__(256) void scan_partial(const int* __restrict__ cnt,
                                                    int* __restrict__ bsum, int n) {
    int i = blockIdx.x * 256 + threadIdx.x;
    int v = (i < n) ? cnt[i] : 0;
#pragma unroll
    for (int d = 32; d > 0; d >>= 1) v += __shfl_down(v, d);
    __shared__ int ws[4];
    int lane = threadIdx.x & 63, w = threadIdx.x >> 6;
    if (lane == 0) ws[w] = v;
    __syncthreads();
    if (threadIdx.x == 0) bsum[blockIdx.x] = ws[0] + ws[1] + ws[2] + ws[3];
}

// ---------------------------------------------------------------------------
// scan phase 2 (fused base+write): every block redundantly reduces bsum to get
// its base and the grand total, then writes its 256 exclusive offsets.
// ---------------------------------------------------------------------------
__global__ __launch_bounds__(256) void scan_write2(const int* __restrict__ cnt,
                                                   const int* __restrict__ bsum,
                                                   int* __restrict__ off, int n, int nb) {
    int t = threadIdx.x, b = blockIdx.x;
    int va = (t < nb) ? bsum[t] : 0;
    int vb = (t < b) ? va : 0;
    int ra = va, rb = vb;
#pragma unroll
    for (int d = 32; d > 0; d >>= 1) { ra += __shfl_down(ra, d); rb += __shfl_down(rb, d); }
    __shared__ int sa[4], sb[4], ws2[4];
    int lane = t & 63, w = t >> 6;
    if (lane == 0) { sa[w] = ra; sb[w] = rb; }
    __syncthreads();
    int total = sa[0] + sa[1] + sa[2] + sa[3];
    int base  = sb[0] + sb[1] + sb[2] + sb[3];
    int i = b * 256 + t;
    int v = (i < n) ? cnt[i] : 0;
    int x = v;
#pragma unroll
    for (int d = 1; d < 64; d <<= 1) { int up = __shfl_up(x, d); if (lane >= d) x += up; }
    if (lane == 63) ws2[w] = x;
    __syncthreads();
    for (int ww = 0; ww < w; ++ww) base += ws2[ww];
    if (i < n) off[i] = base + x - v;
    if (b == (int)gridDim.x - 1 && t == 0) off[n] = total;
}

// ---------------------------------------------------------------------------
// scatter: counting-sort srcs by dst; also seeds the ssort[E] pad slot
// ---------------------------------------------------------------------------
__global__ void scatter_kernel(const int* __restrict__ src, const int* __restrict__ dst,
                               const int* __restrict__ off, int* __restrict__ cur,
                               int* __restrict__ ssort, int E) {
    int e = blockIdx.x * blockDim.x + threadIdx.x;
    if (e == 0) ssort[E] = 0;                    // pad for gather prefetch
    if (e < E) {
        int d = dst[e];
        int p = atomicAdd(&cur[d], 1);
        ssort[off[d] + p] = src[e];
    }
}

// ---------------------------------------------------------------------------
// gather: one wave per dst node, channel pair per lane (one dwordx2/edge).
// Logits pre-scaled by log2e -> raw v_exp_f32. Scalarized wid -> s_loads for
// off/ssort; unconditional 2-deep software pipeline (ssort padded to E+1).
// ---------------------------------------------------------------------------
__global__ __launch_bounds__(256) void gather_kernel(
    const unsigned short* __restrict__ gsv, const unsigned short* __restrict__ fdh,
    const int* __restrict__ off, const int* __restrict__ ssort,
    float* __restrict__ out, int n) {
    int wid = __builtin_amdgcn_readfirstlane((int)((blockIdx.x * 256 + threadIdx.x) >> 6));
    int lane = threadIdx.x & 63;
    if (wid >= n) return;
    float2 fd = __half22float2(*(const __half2*)(fdh + (size_t)wid * 128 + lane * 2));
    float nx = 0.f, ny = 0.f, dx = 0.f, dy = 0.f;
    int beg = off[wid], end = off[wid + 1];
    if (beg < end) {
        int sA = ssort[beg];
        uint2 gA = *(const uint2*)(gsv + (size_t)sA * 256 + lane * 4);
        for (int i = beg; i < end; ++i) {
            int sB = ssort[i + 1];                                   // i+1 <= E
            uint2 gB = *(const uint2*)(gsv + (size_t)sB * 256 + lane * 4);
            float2 fs = __half22float2(*(const __half2*)&gA.x);
            float2 fv = __half22float2(*(const __half2*)&gA.y);
            float a0 = fs.x + fd.x, a1 = fs.y + fd.y;
            a0 = fmaf(fminf(a0, 0.f), -0.8f, a0);    // leaky_relu (scale-safe)
            a1 = fmaf(fminf(a1, 0.f), -0.8f, a1);
            float x0 = EXP2F(a0), x1 = EXP2F(a1);
            dx += x0; dy += x1;
            nx = fmaf(x0, fv.x, nx); ny = fmaf(x1, fv.y, ny);
            gA = gB;
        }
    }
    float2 o;
    o.x = (dx > 0.f) ? nx / dx : 0.f;
    o.y = (dy > 0.f) ? ny / dy : 0.f;
    *(float2*)&out[(size_t)wid * HD + lane * 2] = o;
}

// ---------------------------------------------------------------------------
extern "C" void kernel_launch(void* const* d_in, const int* in_sizes, int n_in,
                              void* d_out, int out_size, void* d_ws, size_t ws_size,
                              hipStream_t stream) {
    const float* feat  = (const float*)d_in[0];
    const float* W_src = (const float*)d_in[1];
    const float* b_src = (const float*)d_in[2];
    const float* W_dst = (const float*)d_in[3];
    const float* b_dst = (const float*)d_in[4];
    const float* W_v   = (const float*)d_in[5];
    const float* b_v   = (const float*)d_in[6];
    const int*   src   = (const int*)d_in[7];
    const int*   dst   = (const int*)d_in[8];
    float* out = (float*)d_out;

    // workspace layout
    unsigned short* gsv = (unsigned short*)d_ws;                 // N*256 u16
    unsigned short* fdh = gsv + (size_t)N_NODES * 256;           // N*128 u16
    unsigned short* Bsw = fdh + (size_t)N_NODES * 128;           // 49152 u16
    int*   cnt  = (int*)(Bsw + 24 * 4 * 64 * 8);                 // N
    int*   cur  = cnt + N_NODES;                                 // N
    int*   off  = cur + N_NODES;                                 // N+1
    int*   bsum = off + (N_NODES + 1);                           // 256
    int*   ssort = bsum + 256;                                   // E+1

    const int nb = (N_NODES + 255) / 256;                        // 196

    prep_zero_kernel<<<nb, 256, 0, stream>>>(W_src, W_dst, W_v, Bsw, cnt, cur);

    projcount_kernel<<<PGRID + CGRID, 256, 0, stream>>>(
        feat, Bsw, b_src, b_dst, b_v, gsv, fdh, dst, cnt);

    scan_partial<<<nb, 256, 0, stream>>>(cnt, bsum, N_NODES);
    scan_write2<<<nb, 256, 0, stream>>>(cnt, bsum, off, N_NODES, nb);

    scatter_kernel<<<(N_EDGES + 255) / 256, 256, 0, stream>>>(src, dst, off, cur, ssort, N_EDGES);

    int ggrid = (N_NODES * 64 + 255) / 256;                      // 12500
    gather_kernel<<<ggrid, 256, 0, stream>>>(gsv, fdh, off, ssort, out, N_NODES);
}

// Round 6
// 196.149 us; speedup vs baseline: 2.5151x; 1.2676x over previous
//
#include <hip/hip_runtime.h>
#include <hip/hip_fp16.h>

#define N_NODES 50000
#define N_EDGES 800000
#define IN_FEATS 128
#define HD 128            // HEADS*OUT_FEATS
#define LOG2E 1.4426950408889634f

#define NB1 200           // pass-1 radix blocks
#define EPB1 4000         // edges per pass-1 block (200*4000 == E exactly)
#define NBUK 196          // buckets = ceil(N_NODES/256)
#define MTAB (NBUK * NB1) // 39200 table entries
#define MB_SCAN 154       // ceil(MTAB/256)
#define EBUF 6144         // LDS edge staging per bucket (mean 4081)

typedef __attribute__((ext_vector_type(8))) short bf16x8;
typedef __attribute__((ext_vector_type(4))) float floatx4;

#if __has_builtin(__builtin_amdgcn_exp2f)
#define EXP2F(x) __builtin_amdgcn_exp2f(x)
#else
#define EXP2F(x) __expf((x) * 0.6931471805599453f)
#endif

static __device__ __forceinline__ unsigned short f2bf(float x) {
    unsigned int u = __float_as_uint(x);
    return (unsigned short)((u + 0x7FFFu + ((u >> 16) & 1u)) >> 16);   // RN-even
}
static __device__ __forceinline__ float bf2f(unsigned short h) {
    return __uint_as_float((unsigned int)h << 16);
}
static __device__ __forceinline__ unsigned int pk(float a, float b) {
    return (unsigned int)__half_as_ushort(__float2half(a)) |
           ((unsigned int)__half_as_ushort(__float2half(b)) << 16);
}

// ---------------------------------------------------------------------------
// prep: swizzle W into MFMA A-operand fragment order (bf16), pre-scaled by
// log2e for src/dst (softmax exp -> exp2).
// ---------------------------------------------------------------------------
__global__ __launch_bounds__(256) void prep_kernel(
    const float* __restrict__ W0, const float* __restrict__ W1,
    const float* __restrict__ W2, unsigned short* __restrict__ Bsw) {
    int idx = blockIdx.x * 256 + threadIdx.x;
    if (idx >= 24 * 4 * 64 * 8) return;
    int j = idx & 7;
    int l = (idx >> 3) & 63;
    int q = (idx >> 9) & 3;
    int t = idx >> 11;                       // 0..23
    int k = q * 32 + ((l >> 4) << 3) + j;
    int c = ((t & 7) << 4) + (l & 15);
    int m = t >> 3;
    const float* W = (m == 0) ? W0 : ((m == 1) ? W1 : W2);
    float w = W[(size_t)c * IN_FEATS + k];
    if (m < 2) w *= LOG2E;
    Bsw[idx] = f2bf(w);
}

// ---------------------------------------------------------------------------
// Fused MFMA projection + pass-1 radix histogram (LDS atomics only).
// ---------------------------------------------------------------------------
#define PGRID 782        // ceil((N_NODES/16)/4)
__global__ __launch_bounds__(256) void proj_hist_kernel(
    const float* __restrict__ feat, const unsigned short* __restrict__ Bsw,
    const float* __restrict__ b_src, const float* __restrict__ b_dst,
    const float* __restrict__ b_v,
    unsigned short* __restrict__ gsv, unsigned short* __restrict__ fdh,
    const int* __restrict__ dst, int* __restrict__ Htab) {
    __shared__ int h[NBUK];
    if (blockIdx.x >= PGRID) {
        int blk = blockIdx.x - PGRID;
        for (int i = threadIdx.x; i < NBUK; i += 256) h[i] = 0;
        __syncthreads();
        int base = blk * EPB1;
        for (int i = threadIdx.x; i < EPB1; i += 256)
            atomicAdd(&h[dst[base + i] >> 8], 1);
        __syncthreads();
        for (int b = threadIdx.x; b < NBUK; b += 256)
            Htab[b * NB1 + blk] = h[b];
        return;
    }
    int wave = threadIdx.x >> 6, lane = threadIdx.x & 63;
    int tile = blockIdx.x * 4 + wave;
    if (tile >= N_NODES / 16) return;
    int row0 = tile * 16;
    int r16 = lane & 15, quad = lane >> 4;
    size_t node = (size_t)(row0 + r16);

    bf16x8 Fh[4], Fl[4];
    const float* frow = feat + node * IN_FEATS + quad * 8;
#pragma unroll
    for (int q = 0; q < 4; ++q) {
        float4 x0 = *(const float4*)(frow + q * 32);
        float4 x1 = *(const float4*)(frow + q * 32 + 4);
        float xs[8] = {x0.x, x0.y, x0.z, x0.w, x1.x, x1.y, x1.z, x1.w};
#pragma unroll
        for (int j = 0; j < 8; ++j) {
            unsigned short hh = f2bf(xs[j]);
            Fh[q][j] = (short)hh;
            Fl[q][j] = (short)f2bf(xs[j] - bf2f(hh));
        }
    }

#pragma unroll 1
    for (int tt = 0; tt < 8; ++tt) {
        floatx4 as = {0.f,0.f,0.f,0.f}, ad = {0.f,0.f,0.f,0.f}, av = {0.f,0.f,0.f,0.f};
#pragma unroll
        for (int q = 0; q < 4; ++q) {
            bf16x8 ws = *(const bf16x8*)(Bsw + ((((tt)      * 4 + q) * 64 + lane) << 3));
            bf16x8 wd = *(const bf16x8*)(Bsw + ((((8 + tt)  * 4 + q) * 64 + lane) << 3));
            bf16x8 wv = *(const bf16x8*)(Bsw + ((((16 + tt) * 4 + q) * 64 + lane) << 3));
            as = __builtin_amdgcn_mfma_f32_16x16x32_bf16(ws, Fh[q], as, 0, 0, 0);
            as = __builtin_amdgcn_mfma_f32_16x16x32_bf16(ws, Fl[q], as, 0, 0, 0);
            ad = __builtin_amdgcn_mfma_f32_16x16x32_bf16(wd, Fh[q], ad, 0, 0, 0);
            ad = __builtin_amdgcn_mfma_f32_16x16x32_bf16(wd, Fl[q], ad, 0, 0, 0);
            av = __builtin_amdgcn_mfma_f32_16x16x32_bf16(wv, Fh[q], av, 0, 0, 0);
            av = __builtin_amdgcn_mfma_f32_16x16x32_bf16(wv, Fl[q], av, 0, 0, 0);
        }
        int cbase = (tt << 4) + (quad << 2);
        float4 bs = *(const float4*)(b_src + cbase);
        float4 bd = *(const float4*)(b_dst + cbase);
        float4 bv = *(const float4*)(b_v   + cbase);
        uint4 o;
        o.x = pk(as[0] + bs.x * LOG2E, as[1] + bs.y * LOG2E);
        o.y = pk(av[0] + bv.x,         av[1] + bv.y);
        o.z = pk(as[2] + bs.z * LOG2E, as[3] + bs.w * LOG2E);
        o.w = pk(av[2] + bv.z,         av[3] + bv.w);
        *(uint4*)(gsv + node * 256 + (cbase << 1)) = o;
        uint2 od;
        od.x = pk(ad[0] + bd.x * LOG2E, ad[1] + bd.y * LOG2E);
        od.y = pk(ad[2] + bd.z * LOG2E, ad[3] + bd.w * LOG2E);
        *(uint2*)(fdh + node * 128 + cbase) = od;
    }
}

// ---------------------------------------------------------------------------
// scan phase 1: per-block sums (256 each) of Htab
// ---------------------------------------------------------------------------
__global__ __launch_bounds__(256) void scan_partial(const int* __restrict__ cnt,
                                                    int* __restrict__ bsum, int n) {
    int i = blockIdx.x * 256 + threadIdx.x;
    int v = (i < n) ? cnt[i] : 0;
#pragma unroll
    for (int d = 32; d > 0; d >>= 1) v += __shfl_down(v, d);
    __shared__ int ws[4];
    int lane = threadIdx.x & 63, w = threadIdx.x >> 6;
    if (lane == 0) ws[w] = v;
    __syncthreads();
    if (threadIdx.x == 0) bsum[blockIdx.x] = ws[0] + ws[1] + ws[2] + ws[3];
}

// ---------------------------------------------------------------------------
// scan phase 2: every block redundantly reduces bsum for its base, then writes
// its 256 exclusive offsets; last block writes grand total at out[n].
// ---------------------------------------------------------------------------
__global__ __launch_bounds__(256) void scan_write2(const int* __restrict__ cnt,
                                                   const int* __restrict__ bsum,
                                                   int* __restrict__ outp, int n, int nb) {
    int t = threadIdx.x, b = blockIdx.x;
    int va = (t < nb) ? bsum[t] : 0;
    int vb = (t < b) ? va : 0;
    int ra = va, rb = vb;
#pragma unroll
    for (int d = 32; d > 0; d >>= 1) { ra += __shfl_down(ra, d); rb += __shfl_down(rb, d); }
    __shared__ int sa[4], sb[4], ws2[4];
    int lane = t & 63, w = t >> 6;
    if (lane == 0) { sa[w] = ra; sb[w] = rb; }
    __syncthreads();
    int total = sa[0] + sa[1] + sa[2] + sa[3];
    int base  = sb[0] + sb[1] + sb[2] + sb[3];
    int i = b * 256 + t;
    int v = (i < n) ? cnt[i] : 0;
    int x = v;
#pragma unroll
    for (int d = 1; d < 64; d <<= 1) { int up = __shfl_up(x, d); if (lane >= d) x += up; }
    if (lane == 63) ws2[w] = x;
    __syncthreads();
    for (int ww = 0; ww < w; ++ww) base += ws2[ww];
    if (i < n) outp[i] = base + x - v;
    if (b == (int)gridDim.x - 1 && t == 0) outp[n] = total;
}

// ---------------------------------------------------------------------------
// pass-1 scatter: deterministic positions from scanned table; LDS cursors.
// Packs (dst&255)<<16 | src into tmp, bucketed by dst>>8.
// ---------------------------------------------------------------------------
__global__ __launch_bounds__(256) void scatter1_kernel(
    const int* __restrict__ src, const int* __restrict__ dst,
    const int* __restrict__ HtabS, unsigned int* __restrict__ tmp) {
    __shared__ int cur[NBUK];
    int blk = blockIdx.x;
    for (int b = threadIdx.x; b < NBUK; b += 256) cur[b] = HtabS[b * NB1 + blk];
    __syncthreads();
    int base = blk * EPB1;
    for (int i = threadIdx.x; i < EPB1; i += 256) {
        int d = dst[base + i];
        int s = src[base + i];
        int p = atomicAdd(&cur[d >> 8], 1);          // LDS atomic
        tmp[p] = (unsigned int)s | ((unsigned int)(d & 255) << 16);
    }
}

// ---------------------------------------------------------------------------
// pass-2 bin: one block per bucket (256 dst nodes). Stage bucket edges in LDS,
// 256-bin count + exclusive scan, emit off[] and dst-sorted ssort[].
// ---------------------------------------------------------------------------
__global__ __launch_bounds__(256) void bin_kernel(
    const unsigned int* __restrict__ tmp, const int* __restrict__ HtabS,
    int* __restrict__ off, int* __restrict__ ssort) {
    __shared__ unsigned int ebuf[EBUF];
    __shared__ int cnt_l[256];
    __shared__ int wsum[4];
    int b = blockIdx.x, t = threadIdx.x;
    int start = HtabS[b * NB1];
    int end = (b == NBUK - 1) ? N_EDGES : HtabS[(b + 1) * NB1];
    int cnt0 = end - start;
    cnt_l[t] = 0;
    __syncthreads();
    bool staged = (cnt0 <= EBUF);
    for (int i = t; i < cnt0; i += 256) {
        unsigned int e = tmp[start + i];
        if (staged) ebuf[i] = e;
        atomicAdd(&cnt_l[e >> 16], 1);
    }
    __syncthreads();
    int v = cnt_l[t];
    int lane = t & 63, w = t >> 6;
    int x = v;
#pragma unroll
    for (int d = 1; d < 64; d <<= 1) { int up = __shfl_up(x, d); if (lane >= d) x += up; }
    if (lane == 63) wsum[w] = x;
    __syncthreads();
    int basex = 0;
    for (int ww = 0; ww < w; ++ww) basex += wsum[ww];
    int excl = basex + x - v;                  // exclusive within bucket
    int node = b * 256 + t;
    if (node < N_NODES) off[node] = start + excl;
    if (b == NBUK - 1 && t == 0) { off[N_NODES] = N_EDGES; ssort[N_EDGES] = 0; }
    __syncthreads();
    cnt_l[t] = excl;                           // becomes cursor
    __syncthreads();
    for (int i = t; i < cnt0; i += 256) {
        unsigned int e = staged ? ebuf[i] : tmp[start + i];
        int p = atomicAdd(&cnt_l[e >> 16], 1);
        ssort[start + p] = (int)(e & 0xFFFFu);
    }
}

// ---------------------------------------------------------------------------
// gather: one wave per dst node, channel pair per lane. Two independent
// pipelined edge streams (ILP-2); fp32 logit math; exp2 (pre-scaled).
// ---------------------------------------------------------------------------
__global__ __launch_bounds__(256) void gather_kernel(
    const unsigned short* __restrict__ gsv, const unsigned short* __restrict__ fdh,
    const int* __restrict__ off, const int* __restrict__ ssort,
    float* __restrict__ out, int n) {
    int wid = __builtin_amdgcn_readfirstlane((int)((blockIdx.x * 256 + threadIdx.x) >> 6));
    int lane = threadIdx.x & 63;
    if (wid >= n) return;
    float2 fd = __half22float2(*(const __half2*)(fdh + (size_t)wid * 128 + lane * 2));

    float nxA = 0.f, nyA = 0.f, dxA = 0.f, dyA = 0.f;
    float nxB = 0.f, nyB = 0.f, dxB = 0.f, dyB = 0.f;
    int beg = off[wid], end = off[wid + 1];
    int mid = (beg + end) >> 1;
    int LA = mid - beg, LB = end - mid;        // LB == LA or LA+1

#define EDGE_UPD(g, valid, dxv, dyv, nxv, nyv) {                              \
        float2 fs = __half22float2(*(const __half2*)&(g).x);                  \
        float a0 = fs.x + fd.x, a1 = fs.y + fd.y;                             \
        a0 = fmaf(fminf(a0, 0.f), -0.8f, a0);                                 \
        a1 = fmaf(fminf(a1, 0.f), -0.8f, a1);                                 \
        float x0 = EXP2F(a0), x1 = EXP2F(a1);                                 \
        if (!(valid)) { x0 = 0.f; x1 = 0.f; }                                 \
        float2 fv = __half22float2(*(const __half2*)&(g).y);                  \
        dxv += x0; dyv += x1;                                                 \
        nxv = fmaf(x0, fv.x, nxv); nyv = fmaf(x1, fv.y, nyv); }

    if (LB > 0) {
        int sA = ssort[beg];
        int sB = ssort[mid];
        uint2 gA = *(const uint2*)(gsv + (size_t)sA * 256 + lane * 4);
        uint2 gB = *(const uint2*)(gsv + (size_t)sB * 256 + lane * 4);
        for (int k = 0; k < LB - 1; ++k) {
            int sA2 = ssort[beg + k + 1];      // <= mid <= E, always safe
            int sB2 = ssort[mid + k + 1];      // <= end <= E, always safe
            uint2 gA2 = *(const uint2*)(gsv + (size_t)sA2 * 256 + lane * 4);
            uint2 gB2 = *(const uint2*)(gsv + (size_t)sB2 * 256 + lane * 4);
            EDGE_UPD(gA, 1, dxA, dyA, nxA, nyA);
            EDGE_UPD(gB, 1, dxB, dyB, nxB, nyB);
            gA = gA2; gB = gB2;
        }
        EDGE_UPD(gA, (LB - 1) < LA, dxA, dyA, nxA, nyA);
        EDGE_UPD(gB, 1, dxB, dyB, nxB, nyB);
    }
    float dx = dxA + dxB, dy = dyA + dyB;
    float nx = nxA + nxB, ny = nyA + nyB;
    float2 o;
    o.x = (dx > 0.f) ? nx / dx : 0.f;
    o.y = (dy > 0.f) ? ny / dy : 0.f;
    *(float2*)&out[(size_t)wid * HD + lane * 2] = o;
#undef EDGE_UPD
}

// ---------------------------------------------------------------------------
extern "C" void kernel_launch(void* const* d_in, const int* in_sizes, int n_in,
                              void* d_out, int out_size, void* d_ws, size_t ws_size,
                              hipStream_t stream) {
    const float* feat  = (const float*)d_in[0];
    const float* W_src = (const float*)d_in[1];
    const float* b_src = (const float*)d_in[2];
    const float* W_dst = (const float*)d_in[3];
    const float* b_dst = (const float*)d_in[4];
    const float* W_v   = (const float*)d_in[5];
    const float* b_v   = (const float*)d_in[6];
    const int*   src   = (const int*)d_in[7];
    const int*   dst   = (const int*)d_in[8];
    float* out = (float*)d_out;

    // workspace layout
    unsigned short* gsv = (unsigned short*)d_ws;                 // N*256 u16
    unsigned short* fdh = gsv + (size_t)N_NODES * 256;           // N*128 u16
    unsigned short* Bsw = fdh + (size_t)N_NODES * 128;           // 49152 u16
    int* Htab  = (int*)(Bsw + 24 * 4 * 64 * 8);                  // MTAB
    int* HtabS = Htab + MTAB;                                    // MTAB+1
    int* bsum  = HtabS + MTAB + 1;                               // 256
    int* off   = bsum + 256;                                     // N+1
    int* ssort = off + (N_NODES + 1);                            // E+1
    unsigned int* tmp = (unsigned int*)(ssort + N_EDGES + 1);    // E

    prep_kernel<<<192, 256, 0, stream>>>(W_src, W_dst, W_v, Bsw);

    proj_hist_kernel<<<PGRID + NB1, 256, 0, stream>>>(
        feat, Bsw, b_src, b_dst, b_v, gsv, fdh, dst, Htab);

    scan_partial<<<MB_SCAN, 256, 0, stream>>>(Htab, bsum, MTAB);
    scan_write2<<<MB_SCAN, 256, 0, stream>>>(Htab, bsum, HtabS, MTAB, MB_SCAN);

    scatter1_kernel<<<NB1, 256, 0, stream>>>(src, dst, HtabS, tmp);
    bin_kernel<<<NBUK, 256, 0, stream>>>(tmp, HtabS, off, ssort);

    gather_kernel<<<(N_NODES * 64) / 256, 256, 0, stream>>>(gsv, fdh, off, ssort, out, N_NODES);
}